// Round 1
// baseline (1105.242 us; speedup 1.0000x reference)
//
#include <hip/hip_runtime.h>
#include <math.h>

#define NN 50000
#define EE 800000
#define D 128
#define EDIM 32
#define LL 3
#define NT 2
#define ET 3
#define NB 196   // ceil(NN/256)

// ---------------- histogram of dst ----------------
__global__ __launch_bounds__(256) void k_hist(const int* __restrict__ dst, int* __restrict__ deg) {
    int e = blockIdx.x * 256 + threadIdx.x;
    if (e < EE) atomicAdd(&deg[dst[e]], 1);
}

// ---------------- 2-level exclusive scan ----------------
__global__ __launch_bounds__(256) void k_scan_bsum(const int* __restrict__ deg, int* __restrict__ bsum) {
    __shared__ int s[256];
    int t = threadIdx.x;
    int d = blockIdx.x * 256 + t;
    s[t] = (d < NN) ? deg[d] : 0;
    __syncthreads();
    for (int st = 128; st > 0; st >>= 1) {
        if (t < st) s[t] += s[t + st];
        __syncthreads();
    }
    if (t == 0) bsum[blockIdx.x] = s[0];
}

__global__ __launch_bounds__(256) void k_scan_boff(const int* __restrict__ bsum, int* __restrict__ boff) {
    __shared__ int s[256];
    int t = threadIdx.x;
    s[t] = (t < NB) ? bsum[t] : 0;
    __syncthreads();
    for (int st = 1; st < 256; st <<= 1) {
        int add = (t >= st) ? s[t - st] : 0;
        __syncthreads();
        s[t] += add;
        __syncthreads();
    }
    if (t < NB) boff[t] = (t == 0) ? 0 : s[t - 1];
}

__global__ __launch_bounds__(256) void k_scan_offs(const int* __restrict__ deg, const int* __restrict__ boff,
                                                   int* __restrict__ offs, int* __restrict__ cur) {
    __shared__ int s[256];
    int t = threadIdx.x;
    int d = blockIdx.x * 256 + t;
    int v = (d < NN) ? deg[d] : 0;
    s[t] = v;
    __syncthreads();
    for (int st = 1; st < 256; st <<= 1) {
        int add = (t >= st) ? s[t - st] : 0;
        __syncthreads();
        s[t] += add;
        __syncthreads();
    }
    if (d < NN) {
        int excl = s[t] - v + boff[blockIdx.x];
        offs[d] = excl;
        cur[d]  = excl;
    }
}

// ------------- per-edge scalars (all 3 layers) + scatter into dst-sorted order -------------
__global__ __launch_bounds__(256) void k_edge(const float* __restrict__ edge_attr,
                                              const float* __restrict__ edge_W,
                                              const float* __restrict__ edge_b,
                                              const float* __restrict__ emb,
                                              const int* __restrict__ ei,
                                              const int* __restrict__ etype,
                                              int* __restrict__ cur,
                                              int* __restrict__ ssrc,
                                              float* __restrict__ As,
                                              float* __restrict__ Bs) {
    __shared__ float eWl[LL * ET * 2 * EDIM];   // 576 floats
    __shared__ float ebd[LL * ET * 2];          // emb·eW + eb, 18 floats
    int t0 = threadIdx.x;
    for (int i = t0; i < LL * ET * 2 * EDIM; i += 256) eWl[i] = edge_W[i];
    __syncthreads();
    if (t0 < LL * ET * 2) {
        int l = t0 / (ET * 2);
        int rem = t0 % (ET * 2);
        int tt = rem / 2;
        float sum = edge_b[t0];
        const float* em = emb + (l * ET + tt) * EDIM;
        const float* w  = eWl + t0 * EDIM;
        for (int c = 0; c < EDIM; c++) sum += em[c] * w[c];
        ebd[t0] = sum;
    }
    __syncthreads();
    int e = blockIdx.x * 256 + t0;
    if (e >= EE) return;

    float a[EDIM];
    const float4* ap = (const float4*)(edge_attr + (size_t)e * EDIM);
#pragma unroll
    for (int i = 0; i < EDIM / 4; i++) {
        float4 v = ap[i];
        a[4 * i + 0] = v.x; a[4 * i + 1] = v.y; a[4 * i + 2] = v.z; a[4 * i + 3] = v.w;
    }
    int tt = etype[e];
    float dir  = a[EDIM - 2];
    float pump = a[EDIM - 1];
    float sign = dir * 2.f - 1.f;
    float speed = pump * (dir > 0.f ? dir : 1.f);
    int src = ei[e];
    int dst = ei[EE + e];
    int pos = atomicAdd(&cur[dst], 1);
    ssrc[pos] = src;
#pragma unroll
    for (int l = 0; l < LL; l++) {
        const float* w0 = eWl + ((l * ET + tt) * 2 + 0) * EDIM;
        const float* w1 = w0 + EDIM;
        float r0 = ebd[(l * ET + tt) * 2 + 0];
        float r1 = ebd[(l * ET + tt) * 2 + 1];
#pragma unroll
        for (int c = 0; c < EDIM; c++) { r0 += a[c] * w0[c]; r1 += a[c] * w1[c]; }
        // softplus, numerically stable
        float gain = fmaxf(r0, 0.f) + log1pf(expf(-fabsf(r0)));
        float bias = 0.f;
        if (tt == 1) { gain *= speed; bias = r1 * speed; }  // PUMP == 1
        As[l * EE + pos] = sign * gain;
        Bs[l * EE + pos] = sign * bias;
    }
}

// ------------- per-node gather-accumulate: aggr[d] = sum A*h[src] - sA*h[d] + sB -------------
__global__ __launch_bounds__(128) void k_gather(const float* __restrict__ h,
                                                const int* __restrict__ offs,
                                                const int* __restrict__ deg,
                                                const int* __restrict__ ssrc,
                                                const float* __restrict__ As,
                                                const float* __restrict__ Bs,
                                                int layer,
                                                float* __restrict__ aggr) {
    int d = blockIdx.x;
    int f = threadIdx.x;
    int start = offs[d];
    int n = deg[d];
    const float* Al = As + (size_t)layer * EE;
    const float* Bl = Bs + (size_t)layer * EE;
    float acc = 0.f, sA = 0.f, sB = 0.f;
    int s0 = 0; float A0 = 0.f, B0 = 0.f;
    if (n > 0) { s0 = ssrc[start]; A0 = Al[start]; B0 = Bl[start]; }
    for (int k = 0; k < n; k++) {
        int s1 = 0; float A1 = 0.f, B1 = 0.f;
        if (k + 1 < n) {
            int p = start + k + 1;
            s1 = ssrc[p]; A1 = Al[p]; B1 = Bl[p];
        }
        acc += A0 * h[(size_t)s0 * D + f];
        sA += A0; sB += B0;
        s0 = s1; A0 = A1; B0 = B1;
    }
    aggr[(size_t)d * D + f] = acc - sA * h[(size_t)d * D + f] + sB;
}

// ------------- node transform + ReLU + LayerNorm + residual -------------
#define TILE 32
__global__ __launch_bounds__(256) void k_node(const float* __restrict__ aggr,
                                              const float* __restrict__ hprev,
                                              const float* __restrict__ Wg,   // node_W + l*NT*D*D
                                              const float* __restrict__ bg,   // node_b + l*NT*D
                                              const float* __restrict__ lng,
                                              const float* __restrict__ lnb,
                                              const int* __restrict__ ntype,
                                              float* __restrict__ hnext) {
    __shared__ float Wl[D * 68];       // [o][i_half], pad 68  (34.8 KB)
    __shared__ float atile[TILE * 132];// [n][i], pad 132      (16.9 KB)
    __shared__ float mu_s[TILE], rs_s[TILE];
    int tid = threadIdx.x;
    int tt = blockIdx.y;
    int n0 = blockIdx.x * TILE;
    const float* W = Wg + (size_t)tt * D * D;

    // stage aggr tile (coalesced)
    for (int r = 0; r < TILE * D / 256; r++) {
        int flat = r * 256 + tid;
        int n = flat >> 7, i = flat & 127;
        int gn = n0 + n;
        atile[n * 132 + i] = (gn < NN) ? aggr[(size_t)gn * D + i] : 0.f;
    }
    int o = tid & 127, g = tid >> 7;
    float acc[TILE / 2];
#pragma unroll
    for (int i = 0; i < TILE / 2; i++) acc[i] = 0.f;

    for (int half = 0; half < 2; half++) {
        __syncthreads();
        for (int r = 0; r < D * 64 / 256; r++) {
            int gi = r * 256 + tid;
            int oo = gi >> 6, ii = gi & 63;
            Wl[oo * 68 + ii] = W[(size_t)oo * D + half * 64 + ii];
        }
        __syncthreads();
        for (int i = 0; i < 64; i += 4) {
            float4 w4 = *(const float4*)&Wl[o * 68 + i];
#pragma unroll
            for (int nn = 0; nn < TILE / 2; nn++) {
                int n = nn * 2 + g;
                float4 a4 = *(const float4*)&atile[n * 132 + half * 64 + i];
                acc[nn] += w4.x * a4.x + w4.y * a4.y + w4.z * a4.z + w4.w * a4.w;
            }
        }
    }
    __syncthreads();
    // relu(acc + b) back into atile (reused)
    float bo = bg[tt * D + o];
#pragma unroll
    for (int nn = 0; nn < TILE / 2; nn++) {
        int n = nn * 2 + g;
        atile[n * 132 + o] = fmaxf(acc[nn] + bo, 0.f);
    }
    __syncthreads();
    // LN stats: 8 lanes per node
    {
        int n = tid >> 3, j = tid & 7;
        float s = 0.f, s2 = 0.f;
        for (int k = 0; k < 16; k++) {
            float v = atile[n * 132 + j + 8 * k];
            s += v; s2 += v * v;
        }
        s += __shfl_xor(s, 1); s2 += __shfl_xor(s2, 1);
        s += __shfl_xor(s, 2); s2 += __shfl_xor(s2, 2);
        s += __shfl_xor(s, 4); s2 += __shfl_xor(s2, 4);
        if (j == 0) {
            float mu = s * (1.f / 128.f);
            float var = s2 * (1.f / 128.f) - mu * mu;
            mu_s[n] = mu;
            rs_s[n] = rsqrtf(var + 1e-5f);
        }
    }
    __syncthreads();
    // normalize + residual, write only nodes of our type
    for (int r = 0; r < TILE * D / 256; r++) {
        int flat = r * 256 + tid;
        int n = flat >> 7, i = flat & 127;
        int gn = n0 + n;
        if (gn < NN && ntype[gn] == tt) {
            float v = (atile[n * 132 + i] - mu_s[n]) * rs_s[n] * lng[i] + lnb[i] + hprev[(size_t)gn * D + i];
            hnext[(size_t)gn * D + i] = v;
        }
    }
}

// ------------- final FC: out = h @ fc_W.T + fc_b -------------
__global__ __launch_bounds__(256) void k_fc(const float* __restrict__ hin,
                                            const float* __restrict__ W,
                                            const float* __restrict__ bias,
                                            float* __restrict__ out) {
    __shared__ float Wl[D * 68];
    __shared__ float atile[TILE * 132];
    int tid = threadIdx.x;
    int n0 = blockIdx.x * TILE;
    for (int r = 0; r < TILE * D / 256; r++) {
        int flat = r * 256 + tid;
        int n = flat >> 7, i = flat & 127;
        int gn = n0 + n;
        atile[n * 132 + i] = (gn < NN) ? hin[(size_t)gn * D + i] : 0.f;
    }
    int o = tid & 127, g = tid >> 7;
    float acc[TILE / 2];
#pragma unroll
    for (int i = 0; i < TILE / 2; i++) acc[i] = 0.f;
    for (int half = 0; half < 2; half++) {
        __syncthreads();
        for (int r = 0; r < D * 64 / 256; r++) {
            int gi = r * 256 + tid;
            int oo = gi >> 6, ii = gi & 63;
            Wl[oo * 68 + ii] = W[(size_t)oo * D + half * 64 + ii];
        }
        __syncthreads();
        for (int i = 0; i < 64; i += 4) {
            float4 w4 = *(const float4*)&Wl[o * 68 + i];
#pragma unroll
            for (int nn = 0; nn < TILE / 2; nn++) {
                int n = nn * 2 + g;
                float4 a4 = *(const float4*)&atile[n * 132 + half * 64 + i];
                acc[nn] += w4.x * a4.x + w4.y * a4.y + w4.z * a4.z + w4.w * a4.w;
            }
        }
    }
    float bo = bias[o];
#pragma unroll
    for (int nn = 0; nn < TILE / 2; nn++) {
        int gn = n0 + nn * 2 + g;
        if (gn < NN) out[(size_t)gn * D + o] = acc[nn] + bo;
    }
}

extern "C" void kernel_launch(void* const* d_in, const int* in_sizes, int n_in,
                              void* d_out, int out_size, void* d_ws, size_t ws_size,
                              hipStream_t stream) {
    const float* x         = (const float*)d_in[0];
    const float* edge_attr = (const float*)d_in[1];
    const float* node_W    = (const float*)d_in[2];
    const float* node_b    = (const float*)d_in[3];
    const float* edge_W    = (const float*)d_in[4];
    const float* edge_b    = (const float*)d_in[5];
    const float* emb       = (const float*)d_in[6];
    const float* ln_g      = (const float*)d_in[7];
    const float* ln_b      = (const float*)d_in[8];
    const float* fc_W      = (const float*)d_in[9];
    const float* fc_b      = (const float*)d_in[10];
    const int*   edge_index = (const int*)d_in[11];
    const int*   node_type  = (const int*)d_in[12];
    const int*   edge_type  = (const int*)d_in[13];
    float* out = (float*)d_out;

    char* w = (char*)d_ws;
    auto alloc = [&](size_t bytes) {
        void* p = (void*)w;
        w += (bytes + 255) & ~(size_t)255;
        return p;
    };
    float* h0   = (float*)alloc((size_t)NN * D * 4);
    float* h1   = (float*)alloc((size_t)NN * D * 4);
    float* aggr = (float*)alloc((size_t)NN * D * 4);
    float* As   = (float*)alloc((size_t)LL * EE * 4);
    float* Bs   = (float*)alloc((size_t)LL * EE * 4);
    int*   ssrc = (int*)alloc((size_t)EE * 4);
    int*   deg  = (int*)alloc((size_t)NN * 4);
    int*   offs = (int*)alloc((size_t)NN * 4);
    int*   cur  = (int*)alloc((size_t)NN * 4);
    int*   bsum = (int*)alloc(256 * 4);
    int*   boff = (int*)alloc(256 * 4);

    hipMemsetAsync(deg, 0, (size_t)NN * 4, stream);
    k_hist<<<(EE + 255) / 256, 256, 0, stream>>>(edge_index + EE, deg);
    k_scan_bsum<<<NB, 256, 0, stream>>>(deg, bsum);
    k_scan_boff<<<1, 256, 0, stream>>>(bsum, boff);
    k_scan_offs<<<NB, 256, 0, stream>>>(deg, boff, offs, cur);
    k_edge<<<(EE + 255) / 256, 256, 0, stream>>>(edge_attr, edge_W, edge_b, emb,
                                                 edge_index, edge_type, cur, ssrc, As, Bs);

    const int nblk = (NN + TILE - 1) / TILE;  // 1563
    const float* hin = x;
    float* hbufs[2] = {h0, h1};
    for (int l = 0; l < LL; l++) {
        k_gather<<<NN, 128, 0, stream>>>(hin, offs, deg, ssrc, As, Bs, l, aggr);
        float* hout = hbufs[l & 1];
        k_node<<<dim3(nblk, NT), 256, 0, stream>>>(aggr, hin,
                                                   node_W + (size_t)l * NT * D * D,
                                                   node_b + (size_t)l * NT * D,
                                                   ln_g + (size_t)l * D,
                                                   ln_b + (size_t)l * D,
                                                   node_type, hout);
        hin = hout;
    }
    k_fc<<<nblk, 256, 0, stream>>>(hin, fc_W, fc_b, out);
}